// Round 11
// baseline (38.423 us; speedup 1.0000x reference)
//
#include <hip/hip_runtime.h>
#include <math.h>

// Problem sizes (fixed): B=4, N=512, M=512, D=256
#define BB 4
#define NN 512
#define MM 512
#define DD 256

typedef short  s16x8  __attribute__((ext_vector_type(8)));
typedef __bf16 bf16x8 __attribute__((ext_vector_type(8)));
typedef __bf16 bf16x4 __attribute__((ext_vector_type(4)));
typedef float  f32x4  __attribute__((ext_vector_type(4)));
typedef float  f32x8  __attribute__((ext_vector_type(8)));
typedef unsigned short u16x4 __attribute__((ext_vector_type(4)));

static __device__ __forceinline__ f32x4 mfma16(s16x8 a, s16x8 b, f32x4 c) {
    return __builtin_amdgcn_mfma_f32_16x16x32_bf16(
        __builtin_bit_cast(bf16x8, a), __builtin_bit_cast(bf16x8, b), c, 0, 0, 0);
}

// load 8 consecutive f32 (32B-aligned) -> bf16 fragment via v_cvt_pk_bf16_f32
static __device__ __forceinline__ s16x8 cvt8(const float* __restrict__ p) {
    const float4 a = *(const float4*)p;
    const float4 b = *(const float4*)(p + 4);
    f32x8 f;
    f[0] = a.x; f[1] = a.y; f[2] = a.z; f[3] = a.w;
    f[4] = b.x; f[5] = b.y; f[6] = b.z; f[7] = b.w;
    return __builtin_bit_cast(s16x8, __builtin_convertvector(f, bf16x8));
}

// 4 floats -> 4 bf16 (RNE)
static __device__ __forceinline__ u16x4 cvt4(float x, float y, float z, float w) {
    f32x4 f; f[0] = x; f[1] = y; f[2] = z; f[3] = w;
    return __builtin_bit_cast(u16x4, __builtin_convertvector(f, bf16x4));
}

// tanh(x) = 1 - 2/(exp2(2*log2e*x)+1); ~1e-6 abs err
static __device__ __forceinline__ float tanh_fast(float x) {
    const float e = __builtin_amdgcn_exp2f(x * 2.8853900817779268f);
    return fmaf(-2.0f, __builtin_amdgcn_rcpf(e + 1.0f), 1.0f);
}

// ---------------- kernel 1: MFMA projections, balanced halves -------------
// 256 blocks. [0,128):  qs (x rows, Wq full) + v e-slice [0,128)   (c rows)
//             [128,256): ks (c rows, Wk full) + v e-slice [128,256) (c rows)
// Each half: 48 MFMA + 48 cvt8-of-W per thread -> balanced straggler.
__global__ __launch_bounds__(256) void k_proj(
    const float* __restrict__ x, const float* __restrict__ c,
    const float* __restrict__ Wq, const float* __restrict__ bq,
    const float* __restrict__ Wk, const float* __restrict__ Wr,
    const float* __restrict__ Wv, const float* __restrict__ bv,
    float* __restrict__ qs, float* __restrict__ ks,
    unsigned short* __restrict__ vT)
{
    __shared__ float red[4][16];
    const int tid  = threadIdx.x;
    const int lane = tid & 63, w = tid >> 6;
    const int li   = lane & 15, g = lane >> 4;
    const bool isk = blockIdx.x >= 128;
    const int row0 = (blockIdx.x & 127) << 4;
    const int b  = row0 >> 9;
    const int m0 = row0 & 511;
    unsigned short* vTb = vT + (size_t)b * (DD * MM);
    const int e_base = w * 64 + li;        // qs/ks e-coverage (4 waves x 64)
    const int e_v    = (isk ? 128 : 0) + w * 32 + li;  // v e-slice (4 waves x 32)

    if (!isk) {
        // A fragments from x (for qs)
        const float* ap = x + (size_t)(row0 + li) * DD + g * 8;
        s16x8 af[8];
        #pragma unroll
        for (int kk = 0; kk < 8; ++kk) af[kk] = cvt8(ap + kk * 32);
        // A fragments from c (for v-low)
        const float* apc = c + (size_t)(row0 + li) * DD + g * 8;
        s16x8 afc[8];
        #pragma unroll
        for (int kk = 0; kk < 8; ++kk) afc[kk] = cvt8(apc + kk * 32);

        f32x4 acc[4];
        const float* bp[4];
        #pragma unroll
        for (int nt = 0; nt < 4; ++nt) {
            acc[nt] = (f32x4){0.f, 0.f, 0.f, 0.f};
            bp[nt] = Wq + (size_t)(e_base + nt * 16) * DD + g * 8;
        }
        f32x4 avv[2];
        const float* bpv[2];
        #pragma unroll
        for (int nt = 0; nt < 2; ++nt) {
            avv[nt] = (f32x4){0.f, 0.f, 0.f, 0.f};
            bpv[nt] = Wv + (size_t)(e_v + nt * 16) * DD + g * 8;
        }
        #pragma unroll
        for (int kk = 0; kk < 8; ++kk) {
            #pragma unroll
            for (int nt = 0; nt < 4; ++nt)
                acc[nt] = mfma16(af[kk], cvt8(bp[nt] + kk * 32), acc[nt]);
            #pragma unroll
            for (int nt = 0; nt < 2; ++nt)
                avv[nt] = mfma16(afc[kk], cvt8(bpv[nt] + kk * 32), avv[nt]);
        }

        // v-low store
        #pragma unroll
        for (int nt = 0; nt < 2; ++nt) {
            const int e = e_v + nt * 16;
            const float bve = bv[e];
            const u16x4 o = cvt4((avv[nt][0] + bve) * 0.0625f,
                                 (avv[nt][1] + bve) * 0.0625f,
                                 (avv[nt][2] + bve) * 0.0625f,
                                 (avv[nt][3] + bve) * 0.0625f);
            *(u16x4*)(vTb + (size_t)e * MM + m0 + g * 4) = o;
        }

        // qs epilogue
        float p[4] = {0.f, 0.f, 0.f, 0.f};
        #pragma unroll
        for (int nt = 0; nt < 4; ++nt) {
            const int e = e_base + nt * 16;
            const float bqe = bq[e], wre = Wr[e];
            #pragma unroll
            for (int r = 0; r < 4; ++r)
                p[r] += wre * tanh_fast(acc[nt][r] + bqe);
        }
        #pragma unroll
        for (int r = 0; r < 4; ++r) {
            p[r] += __shfl_xor(p[r], 1);
            p[r] += __shfl_xor(p[r], 2);
            p[r] += __shfl_xor(p[r], 4);
            p[r] += __shfl_xor(p[r], 8);
        }
        if (li == 0) {
            #pragma unroll
            for (int r = 0; r < 4; ++r) red[w][g * 4 + r] = p[r];
        }
        __syncthreads();
        if (tid < 16)
            qs[row0 + tid] = red[0][tid] + red[1][tid] + red[2][tid] + red[3][tid];
    } else {
        // A fragments from c (shared by ks and v-high)
        const float* ap = c + (size_t)(row0 + li) * DD + g * 8;
        s16x8 af[8];
        #pragma unroll
        for (int kk = 0; kk < 8; ++kk) af[kk] = cvt8(ap + kk * 32);

        f32x4 acc[4];
        const float* bp[4];
        #pragma unroll
        for (int nt = 0; nt < 4; ++nt) {
            acc[nt] = (f32x4){0.f, 0.f, 0.f, 0.f};
            bp[nt] = Wk + (size_t)(e_base + nt * 16) * DD + g * 8;
        }
        f32x4 avv[2];
        const float* bpv[2];
        #pragma unroll
        for (int nt = 0; nt < 2; ++nt) {
            avv[nt] = (f32x4){0.f, 0.f, 0.f, 0.f};
            bpv[nt] = Wv + (size_t)(e_v + nt * 16) * DD + g * 8;
        }
        #pragma unroll
        for (int kk = 0; kk < 8; ++kk) {
            #pragma unroll
            for (int nt = 0; nt < 4; ++nt)
                acc[nt] = mfma16(af[kk], cvt8(bp[nt] + kk * 32), acc[nt]);
            #pragma unroll
            for (int nt = 0; nt < 2; ++nt)
                avv[nt] = mfma16(af[kk], cvt8(bpv[nt] + kk * 32), avv[nt]);
        }

        // v-high store
        #pragma unroll
        for (int nt = 0; nt < 2; ++nt) {
            const int e = e_v + nt * 16;
            const float bve = bv[e];
            const u16x4 o = cvt4((avv[nt][0] + bve) * 0.0625f,
                                 (avv[nt][1] + bve) * 0.0625f,
                                 (avv[nt][2] + bve) * 0.0625f,
                                 (avv[nt][3] + bve) * 0.0625f);
            *(u16x4*)(vTb + (size_t)e * MM + m0 + g * 4) = o;
        }

        // ks epilogue
        float p[4] = {0.f, 0.f, 0.f, 0.f};
        #pragma unroll
        for (int nt = 0; nt < 4; ++nt) {
            const int e = e_base + nt * 16;
            const float wre = Wr[e];
            #pragma unroll
            for (int r = 0; r < 4; ++r)
                p[r] += wre * tanh_fast(acc[nt][r]);
        }
        #pragma unroll
        for (int r = 0; r < 4; ++r) {
            p[r] += __shfl_xor(p[r], 1);
            p[r] += __shfl_xor(p[r], 2);
            p[r] += __shfl_xor(p[r], 4);
            p[r] += __shfl_xor(p[r], 8);
        }
        if (li == 0) {
            #pragma unroll
            for (int r = 0; r < 4; ++r) red[w][g * 4 + r] = p[r];
        }
        __syncthreads();
        if (tid < 16)
            ks[row0 + tid] = red[0][tid] + red[1][tid] + red[2][tid] + red[3][tid];
    }
}

// ---------------- kernel 2: scores + PV (MFMA) + residual + LayerNorm -----
// 256 blocks x 8 n-rows. vT kk=0..3 prefetched into regs before the score
// phase (T14 issue-early) so L3 latency hides under the tanh VALU work.
__global__ __launch_bounds__(256) void k_main(
    const float* __restrict__ x, const float* __restrict__ mask,
    const float* __restrict__ qs, const float* __restrict__ ks,
    const unsigned short* __restrict__ vT,
    const float* __restrict__ gamma, const float* __restrict__ beta,
    float* __restrict__ out)
{
    __shared__ unsigned short w_lds[16][512];   // 16 KB (rows 0..7 written)
    __shared__ float ksm[MM];                   // 2 KB
    __shared__ float h_lds[16][264];            // 2-way write alias (free)
    const int tid  = threadIdx.x;
    const int lane = tid & 63, w = tid >> 6;
    const int li   = lane & 15, g = lane >> 4;
    const int n0g  = blockIdx.x << 3;           // 8 rows per block
    const int b    = n0g >> 9;

    // vT pointers + early prefetch of kk=0..3 (16 loads in flight)
    const unsigned short* vp[4];
    #pragma unroll
    for (int nt = 0; nt < 4; ++nt)
        vp[nt] = vT + (size_t)b * (DD * MM)
                    + (size_t)(w * 64 + nt * 16 + li) * MM + g * 8;
    s16x8 vpre[4][4];   // [kk][nt]
    #pragma unroll
    for (int kk = 0; kk < 4; ++kk)
        #pragma unroll
        for (int nt = 0; nt < 4; ++nt)
            vpre[kk][nt] = *(const s16x8*)(vp[nt] + kk * 32);

    ksm[tid]       = ks[(b << 9) + tid];
    ksm[tid + 256] = ks[(b << 9) + 256 + tid];
    __syncthreads();

    // scores rows 0..7 -> bf16 swizzled LDS (byte ^= (row&7)<<4)
    char* wbase = (char*)w_lds;
    const float* __restrict__ mrow = mask + (size_t)n0g * MM;
    #pragma unroll
    for (int it = 0; it < 4; ++it) {
        const int L = (it << 10) + (tid << 2);
        const int i = L >> 9;
        const int m = L & 511;
        const float qv = qs[n0g + i];
        const float4 mk = *(const float4*)(mrow + (size_t)i * MM + m);
        const float4 kv = *(const float4*)&ksm[m];
        const u16x4 o = cvt4(fmaxf(tanh_fast(qv + kv.x), 0.f) * mk.x,
                             fmaxf(tanh_fast(qv + kv.y), 0.f) * mk.y,
                             fmaxf(tanh_fast(qv + kv.z), 0.f) * mk.z,
                             fmaxf(tanh_fast(qv + kv.w), 0.f) * mk.w);
        *(u16x4*)(wbase + (i << 10) + ((m << 1) ^ ((i & 7) << 4))) = o;
    }
    __syncthreads();

    // PV: wave w covers e-cols [w*64, w*64+64), K = 512 (16 k-steps)
    f32x4 acc[4];
    #pragma unroll
    for (int nt = 0; nt < 4; ++nt) acc[nt] = (f32x4){0.f, 0.f, 0.f, 0.f};
    const char* arow = wbase + (li << 10);
    const int aswz = (li & 7) << 4;
    #pragma unroll
    for (int kk = 0; kk < 16; ++kk) {
        const s16x8 a = *(const s16x8*)(arow + (((kk << 6) + (g << 4)) ^ aswz));
        #pragma unroll
        for (int nt = 0; nt < 4; ++nt) {
            const s16x8 bfrag = (kk < 4) ? vpre[kk][nt]
                                         : *(const s16x8*)(vp[nt] + kk * 32);
            acc[nt] = mfma16(a, bfrag, acc[nt]);
        }
    }

    // scatter partial h: lane holds D-rows 4g+r, col e
    #pragma unroll
    for (int nt = 0; nt < 4; ++nt) {
        const int e = w * 64 + nt * 16 + li;
        #pragma unroll
        for (int r = 0; r < 4; ++r)
            h_lds[g * 4 + r][e] = acc[nt][r];
    }
    __syncthreads();

    // LN: wave w owns rows {2w, 2w+1}; lane owns 4 contiguous d
    const float4 gm = ((const float4*)gamma)[lane];
    const float4 bt = ((const float4*)beta)[lane];
    #pragma unroll
    for (int rr = 0; rr < 2; ++rr) {
        const int row = (w << 1) + rr;
        const float4 hv = *(const float4*)&h_lds[row][lane << 2];
        const float4 xv = *(const float4*)(x + ((size_t)(n0g + row)) * DD + (lane << 2));
        float4 h;
        h.x = xv.x + hv.x; h.y = xv.y + hv.y;
        h.z = xv.z + hv.z; h.w = xv.w + hv.w;
        float s  = h.x + h.y + h.z + h.w;
        float s2 = h.x * h.x + h.y * h.y + h.z * h.z + h.w * h.w;
        #pragma unroll
        for (int off = 32; off; off >>= 1) {
            s  += __shfl_xor(s, off);
            s2 += __shfl_xor(s2, off);
        }
        const float mean = s * (1.0f / DD);
        const float var  = s2 * (1.0f / DD) - mean * mean;
        const float inv  = rsqrtf(var + 1e-5f);
        float4 o;
        o.x = (h.x - mean) * inv * gm.x + bt.x;
        o.y = (h.y - mean) * inv * gm.y + bt.y;
        o.z = (h.z - mean) * inv * gm.z + bt.z;
        o.w = (h.w - mean) * inv * gm.w + bt.w;
        *(float4*)(out + ((size_t)(n0g + row)) * DD + (lane << 2)) = o;
    }
}

extern "C" void kernel_launch(void* const* d_in, const int* in_sizes, int n_in,
                              void* d_out, int out_size, void* d_ws, size_t ws_size,
                              hipStream_t stream) {
    const float* x     = (const float*)d_in[0];
    const float* c     = (const float*)d_in[1];
    const float* mask  = (const float*)d_in[2];
    const float* Wq    = (const float*)d_in[3];
    const float* bq    = (const float*)d_in[4];
    const float* Wk    = (const float*)d_in[5];
    const float* Wr    = (const float*)d_in[6];
    const float* Wv    = (const float*)d_in[7];
    const float* bv    = (const float*)d_in[8];
    const float* gamma = (const float*)d_in[9];
    const float* beta  = (const float*)d_in[10];
    float* out = (float*)d_out;

    float* ws = (float*)d_ws;
    float* qs  = ws;                                    // 2048 f32
    float* ksb = ws + 2048;                             // 2048 f32
    unsigned short* vT = (unsigned short*)(ws + 4096);  // 524288 bf16 [b][e][m]

    k_proj<<<256, 256, 0, stream>>>(x, c, Wq, bq, Wk, Wr, Wv, bv, qs, ksb, vT);
    k_main<<<256, 256, 0, stream>>>(x, mask, qs, ksb, vT, gamma, beta, out);
}

// Round 12
// 30.859 us; speedup vs baseline: 1.2451x; 1.2451x over previous
//
#include <hip/hip_runtime.h>
#include <math.h>

// Problem sizes (fixed): B=4, N=512, M=512, D=256
#define BB 4
#define NN 512
#define MM 512
#define DD 256

typedef short  s16x8  __attribute__((ext_vector_type(8)));
typedef __bf16 bf16x8 __attribute__((ext_vector_type(8)));
typedef __bf16 bf16x4 __attribute__((ext_vector_type(4)));
typedef float  f32x4  __attribute__((ext_vector_type(4)));
typedef float  f32x8  __attribute__((ext_vector_type(8)));
typedef unsigned short u16x4 __attribute__((ext_vector_type(4)));

static __device__ __forceinline__ f32x4 mfma16(s16x8 a, s16x8 b, f32x4 c) {
    return __builtin_amdgcn_mfma_f32_16x16x32_bf16(
        __builtin_bit_cast(bf16x8, a), __builtin_bit_cast(bf16x8, b), c, 0, 0, 0);
}

// load 8 consecutive f32 (32B-aligned) -> bf16 fragment via v_cvt_pk_bf16_f32
static __device__ __forceinline__ s16x8 cvt8(const float* __restrict__ p) {
    const float4 a = *(const float4*)p;
    const float4 b = *(const float4*)(p + 4);
    f32x8 f;
    f[0] = a.x; f[1] = a.y; f[2] = a.z; f[3] = a.w;
    f[4] = b.x; f[5] = b.y; f[6] = b.z; f[7] = b.w;
    return __builtin_bit_cast(s16x8, __builtin_convertvector(f, bf16x8));
}

// 4 floats -> 4 bf16 (RNE)
static __device__ __forceinline__ u16x4 cvt4(float x, float y, float z, float w) {
    f32x4 f; f[0] = x; f[1] = y; f[2] = z; f[3] = w;
    return __builtin_bit_cast(u16x4, __builtin_convertvector(f, bf16x4));
}

// tanh(x) = 1 - 2/(exp2(2*log2e*x)+1); ~1e-6 abs err
static __device__ __forceinline__ float tanh_fast(float x) {
    const float e = __builtin_amdgcn_exp2f(x * 2.8853900817779268f);
    return fmaf(-2.0f, __builtin_amdgcn_rcpf(e + 1.0f), 1.0f);
}

// ---------------- kernel 1: MFMA projections, 32-row x e-half blocks ------
// 256 blocks. [0,128):  qs-partials  (x rows, Wq e-half)
//             [128,256): ks-partials + vT tile (c rows, Wk/Wv e-half)
// Per-block weight conversion halves vs 16-row full-e blocks (W converted
// once per block): ksv straggler 72 -> 48 cvt8/thread.
// qp/kp[row] = float2 partials {e-half0, e-half1}; k_main sums them.
__global__ __launch_bounds__(256) void k_proj(
    const float* __restrict__ x, const float* __restrict__ c,
    const float* __restrict__ Wq, const float* __restrict__ bq,
    const float* __restrict__ Wk, const float* __restrict__ Wr,
    const float* __restrict__ Wv, const float* __restrict__ bv,
    float* __restrict__ qp, float* __restrict__ kp,
    unsigned short* __restrict__ vT)
{
    __shared__ float red[4][32];
    const int tid  = threadIdx.x;
    const int lane = tid & 63, w = tid >> 6;
    const int li   = lane & 15, g = lane >> 4;
    const bool isk = blockIdx.x >= 128;
    const int idx  = blockIdx.x & 127;
    const int row0 = (idx >> 1) << 5;             // 32 rows per block
    const int eh   = idx & 1;
    const int e_base = (eh << 7) + w * 32 + li;   // 4 waves x 32 e-cols = e-half
    const float* __restrict__ src = isk ? c : x;

    // A fragments for 2 row-tiles: lane supplies A[i=li][k=g*8+t]
    s16x8 af[2][8];
    #pragma unroll
    for (int rt = 0; rt < 2; ++rt) {
        const float* ap = src + (size_t)(row0 + rt * 16 + li) * DD + g * 8;
        #pragma unroll
        for (int kk = 0; kk < 8; ++kk) af[rt][kk] = cvt8(ap + kk * 32);
    }

    if (!isk) {
        f32x4 acc[2][2];   // [rt][nt]
        const float* bp[2];
        #pragma unroll
        for (int nt = 0; nt < 2; ++nt) {
            acc[0][nt] = (f32x4){0.f, 0.f, 0.f, 0.f};
            acc[1][nt] = (f32x4){0.f, 0.f, 0.f, 0.f};
            bp[nt] = Wq + (size_t)(e_base + nt * 16) * DD + g * 8;
        }
        #pragma unroll
        for (int kk = 0; kk < 8; ++kk) {
            const s16x8 b0 = cvt8(bp[0] + kk * 32);
            const s16x8 b1 = cvt8(bp[1] + kk * 32);
            #pragma unroll
            for (int rt = 0; rt < 2; ++rt) {
                acc[rt][0] = mfma16(af[rt][kk], b0, acc[rt][0]);
                acc[rt][1] = mfma16(af[rt][kk], b1, acc[rt][1]);
            }
        }
        float p[2][4] = {{0.f,0.f,0.f,0.f},{0.f,0.f,0.f,0.f}};
        #pragma unroll
        for (int nt = 0; nt < 2; ++nt) {
            const int e = e_base + nt * 16;
            const float bqe = bq[e], wre = Wr[e];
            #pragma unroll
            for (int rt = 0; rt < 2; ++rt)
                #pragma unroll
                for (int r = 0; r < 4; ++r)
                    p[rt][r] += wre * tanh_fast(acc[rt][nt][r] + bqe);
        }
        #pragma unroll
        for (int rt = 0; rt < 2; ++rt)
            #pragma unroll
            for (int r = 0; r < 4; ++r) {
                p[rt][r] += __shfl_xor(p[rt][r], 1);
                p[rt][r] += __shfl_xor(p[rt][r], 2);
                p[rt][r] += __shfl_xor(p[rt][r], 4);
                p[rt][r] += __shfl_xor(p[rt][r], 8);
            }
        if (li == 0)
            #pragma unroll
            for (int rt = 0; rt < 2; ++rt)
                #pragma unroll
                for (int r = 0; r < 4; ++r)
                    red[w][rt * 16 + g * 4 + r] = p[rt][r];
        __syncthreads();
        if (tid < 32)
            qp[((row0 + tid) << 1) + eh] =
                red[0][tid] + red[1][tid] + red[2][tid] + red[3][tid];
    } else {
        f32x4 ak[2][2], av[2][2];
        const float* bpk[2];
        const float* bpv[2];
        #pragma unroll
        for (int nt = 0; nt < 2; ++nt) {
            ak[0][nt] = (f32x4){0.f,0.f,0.f,0.f}; ak[1][nt] = (f32x4){0.f,0.f,0.f,0.f};
            av[0][nt] = (f32x4){0.f,0.f,0.f,0.f}; av[1][nt] = (f32x4){0.f,0.f,0.f,0.f};
            bpk[nt] = Wk + (size_t)(e_base + nt * 16) * DD + g * 8;
            bpv[nt] = Wv + (size_t)(e_base + nt * 16) * DD + g * 8;
        }
        #pragma unroll
        for (int kk = 0; kk < 8; ++kk) {
            const s16x8 k0 = cvt8(bpk[0] + kk * 32);
            const s16x8 k1 = cvt8(bpk[1] + kk * 32);
            const s16x8 v0 = cvt8(bpv[0] + kk * 32);
            const s16x8 v1 = cvt8(bpv[1] + kk * 32);
            #pragma unroll
            for (int rt = 0; rt < 2; ++rt) {
                ak[rt][0] = mfma16(af[rt][kk], k0, ak[rt][0]);
                ak[rt][1] = mfma16(af[rt][kk], k1, ak[rt][1]);
                av[rt][0] = mfma16(af[rt][kk], v0, av[rt][0]);
                av[rt][1] = mfma16(af[rt][kk], v1, av[rt][1]);
            }
        }

        // vT[b][e][m] bf16: lane holds m-rows (m0 + rt*16 + 4g + r) for col e
        const int b  = row0 >> 9;
        const int m0 = row0 & 511;
        unsigned short* vTb = vT + (size_t)b * (DD * MM);
        #pragma unroll
        for (int nt = 0; nt < 2; ++nt) {
            const int e = e_base + nt * 16;
            const float bve = bv[e];
            #pragma unroll
            for (int rt = 0; rt < 2; ++rt) {
                const u16x4 o = cvt4((av[rt][nt][0] + bve) * 0.0625f,
                                     (av[rt][nt][1] + bve) * 0.0625f,
                                     (av[rt][nt][2] + bve) * 0.0625f,
                                     (av[rt][nt][3] + bve) * 0.0625f);
                *(u16x4*)(vTb + (size_t)e * MM + m0 + rt * 16 + g * 4) = o;
            }
        }

        float p[2][4] = {{0.f,0.f,0.f,0.f},{0.f,0.f,0.f,0.f}};
        #pragma unroll
        for (int nt = 0; nt < 2; ++nt) {
            const int e = e_base + nt * 16;
            const float wre = Wr[e];
            #pragma unroll
            for (int rt = 0; rt < 2; ++rt)
                #pragma unroll
                for (int r = 0; r < 4; ++r)
                    p[rt][r] += wre * tanh_fast(ak[rt][nt][r]);
        }
        #pragma unroll
        for (int rt = 0; rt < 2; ++rt)
            #pragma unroll
            for (int r = 0; r < 4; ++r) {
                p[rt][r] += __shfl_xor(p[rt][r], 1);
                p[rt][r] += __shfl_xor(p[rt][r], 2);
                p[rt][r] += __shfl_xor(p[rt][r], 4);
                p[rt][r] += __shfl_xor(p[rt][r], 8);
            }
        if (li == 0)
            #pragma unroll
            for (int rt = 0; rt < 2; ++rt)
                #pragma unroll
                for (int r = 0; r < 4; ++r)
                    red[w][rt * 16 + g * 4 + r] = p[rt][r];
        __syncthreads();
        if (tid < 32)
            kp[((row0 + tid) << 1) + eh] =
                red[0][tid] + red[1][tid] + red[2][tid] + red[3][tid];
    }
}

// ---------------- kernel 2: scores + PV (MFMA) + residual + LayerNorm -----
// 256 blocks x 8 n-rows (identical to the R9 best kernel except qs/ks are
// read as float2 e-half partial pairs and summed on load).
__global__ __launch_bounds__(256) void k_main(
    const float* __restrict__ x, const float* __restrict__ mask,
    const float* __restrict__ qp, const float* __restrict__ kp,
    const unsigned short* __restrict__ vT,
    const float* __restrict__ gamma, const float* __restrict__ beta,
    float* __restrict__ out)
{
    __shared__ unsigned short w_lds[16][512];   // 16 KB (rows 0..7 written)
    __shared__ float ksm[MM];                   // 2 KB
    __shared__ float h_lds[16][264];            // 2-way write alias (free)
    const int tid  = threadIdx.x;
    const int lane = tid & 63, w = tid >> 6;
    const int li   = lane & 15, g = lane >> 4;
    const int n0g  = blockIdx.x << 3;           // 8 rows per block
    const int b    = n0g >> 9;

    // stage ks (sum the two e-half partials)
    const float2* __restrict__ kp2 = (const float2*)kp + (b << 9);
    {
        const float2 a0 = kp2[tid];
        const float2 a1 = kp2[tid + 256];
        ksm[tid]       = a0.x + a0.y;
        ksm[tid + 256] = a1.x + a1.y;
    }
    __syncthreads();

    // scores rows 0..7 -> bf16 swizzled LDS (byte ^= (row&7)<<4)
    char* wbase = (char*)w_lds;
    const float* __restrict__ mrow = mask + (size_t)n0g * MM;
    const float2* __restrict__ qp2 = (const float2*)qp;
    #pragma unroll
    for (int it = 0; it < 4; ++it) {
        const int L = (it << 10) + (tid << 2);
        const int i = L >> 9;
        const int m = L & 511;
        const float2 q2 = qp2[n0g + i];
        const float qv = q2.x + q2.y;
        const float4 mk = *(const float4*)(mrow + (size_t)i * MM + m);
        const float4 kv = *(const float4*)&ksm[m];
        const u16x4 o = cvt4(fmaxf(tanh_fast(qv + kv.x), 0.f) * mk.x,
                             fmaxf(tanh_fast(qv + kv.y), 0.f) * mk.y,
                             fmaxf(tanh_fast(qv + kv.z), 0.f) * mk.z,
                             fmaxf(tanh_fast(qv + kv.w), 0.f) * mk.w);
        *(u16x4*)(wbase + (i << 10) + ((m << 1) ^ ((i & 7) << 4))) = o;
    }
    __syncthreads();

    // PV: wave w covers e-cols [w*64, w*64+64), K = 512 (16 k-steps)
    f32x4 acc[4];
    const unsigned short* vp[4];
    #pragma unroll
    for (int nt = 0; nt < 4; ++nt) {
        acc[nt] = (f32x4){0.f, 0.f, 0.f, 0.f};
        vp[nt] = vT + (size_t)b * (DD * MM)
                    + (size_t)(w * 64 + nt * 16 + li) * MM + g * 8;
    }
    const char* arow = wbase + (li << 10);
    const int aswz = (li & 7) << 4;
    #pragma unroll
    for (int kk = 0; kk < 16; ++kk) {
        const s16x8 a = *(const s16x8*)(arow + (((kk << 6) + (g << 4)) ^ aswz));
        #pragma unroll
        for (int nt = 0; nt < 4; ++nt)
            acc[nt] = mfma16(a, *(const s16x8*)(vp[nt] + kk * 32), acc[nt]);
    }

    // scatter partial h: lane holds D-rows 4g+r, col e
    #pragma unroll
    for (int nt = 0; nt < 4; ++nt) {
        const int e = w * 64 + nt * 16 + li;
        #pragma unroll
        for (int r = 0; r < 4; ++r)
            h_lds[g * 4 + r][e] = acc[nt][r];
    }
    __syncthreads();

    // LN: wave w owns rows {2w, 2w+1}; lane owns 4 contiguous d
    const float4 gm = ((const float4*)gamma)[lane];
    const float4 bt = ((const float4*)beta)[lane];
    #pragma unroll
    for (int rr = 0; rr < 2; ++rr) {
        const int row = (w << 1) + rr;
        const float4 hv = *(const float4*)&h_lds[row][lane << 2];
        const float4 xv = *(const float4*)(x + ((size_t)(n0g + row)) * DD + (lane << 2));
        float4 h;
        h.x = xv.x + hv.x; h.y = xv.y + hv.y;
        h.z = xv.z + hv.z; h.w = xv.w + hv.w;
        float s  = h.x + h.y + h.z + h.w;
        float s2 = h.x * h.x + h.y * h.y + h.z * h.z + h.w * h.w;
        #pragma unroll
        for (int off = 32; off; off >>= 1) {
            s  += __shfl_xor(s, off);
            s2 += __shfl_xor(s2, off);
        }
        const float mean = s * (1.0f / DD);
        const float var  = s2 * (1.0f / DD) - mean * mean;
        const float inv  = rsqrtf(var + 1e-5f);
        float4 o;
        o.x = (h.x - mean) * inv * gm.x + bt.x;
        o.y = (h.y - mean) * inv * gm.y + bt.y;
        o.z = (h.z - mean) * inv * gm.z + bt.z;
        o.w = (h.w - mean) * inv * gm.w + bt.w;
        *(float4*)(out + ((size_t)(n0g + row)) * DD + (lane << 2)) = o;
    }
}

extern "C" void kernel_launch(void* const* d_in, const int* in_sizes, int n_in,
                              void* d_out, int out_size, void* d_ws, size_t ws_size,
                              hipStream_t stream) {
    const float* x     = (const float*)d_in[0];
    const float* c     = (const float*)d_in[1];
    const float* mask  = (const float*)d_in[2];
    const float* Wq    = (const float*)d_in[3];
    const float* bq    = (const float*)d_in[4];
    const float* Wk    = (const float*)d_in[5];
    const float* Wr    = (const float*)d_in[6];
    const float* Wv    = (const float*)d_in[7];
    const float* bv    = (const float*)d_in[8];
    const float* gamma = (const float*)d_in[9];
    const float* beta  = (const float*)d_in[10];
    float* out = (float*)d_out;

    float* ws = (float*)d_ws;
    float* qp = ws;                                     // 4096 f32 (float2/row)
    float* kp = ws + 4096;                              // 4096 f32 (float2/row)
    unsigned short* vT = (unsigned short*)(ws + 8192);  // 524288 bf16 [b][e][m]

    k_proj<<<256, 256, 0, stream>>>(x, c, Wq, bq, Wk, Wr, Wv, bv, qp, kp, vT);
    k_main<<<256, 256, 0, stream>>>(x, mask, qp, kp, vT, gamma, beta, out);
}